// Round 1
// baseline (3070.344 us; speedup 1.0000x reference)
//
#include <hip/hip_runtime.h>
#include <math.h>

#define NA      128
#define NBATCH  2048
#define NTHR    512
#define NIT     300
#define NSUP    20      // 20 super-rounds x 2 bits = 40 bisection rounds, BIT-EXACT
                        // vs the serial NBIS=40 (R7: tau noise amplifies ~4e4x, so
                        // the lo/hi/mid fp sequence must not change)
#define LRC     0.02f
#define EPSC    1e-8f

// ---- wave64 cross-lane reductions via DPP (VALU pipe, no LDS traffic) ----
template <int CTRL>
__device__ __forceinline__ float dpp_sum_step(float x) {
  int s = __builtin_amdgcn_update_dpp(0, __float_as_int(x), CTRL, 0xF, 0xF, true);
  return x + __int_as_float(s);
}
__device__ __forceinline__ float wave_sum64(float x) {
  x = dpp_sum_step<0x111>(x);
  x = dpp_sum_step<0x112>(x);
  x = dpp_sum_step<0x114>(x);
  x = dpp_sum_step<0x118>(x);
  x = dpp_sum_step<0x142>(x);
  x = dpp_sum_step<0x143>(x);
  return x;  // total in lane 63
}
// Three INDEPENDENT reductions with steps interleaved: each chain is 6
// dependent DPP+ADD pairs (~48cy latency); interleaving makes the SIMD
// pipeline them (issue-bound ~75cy total instead of ~144cy serial). Each
// individual chain performs exactly the same op sequence as wave_sum64.
__device__ __forceinline__ void wave_sum64_x3(float& x, float& y, float& z) {
  x = dpp_sum_step<0x111>(x); y = dpp_sum_step<0x111>(y); z = dpp_sum_step<0x111>(z);
  x = dpp_sum_step<0x112>(x); y = dpp_sum_step<0x112>(y); z = dpp_sum_step<0x112>(z);
  x = dpp_sum_step<0x114>(x); y = dpp_sum_step<0x114>(y); z = dpp_sum_step<0x114>(z);
  x = dpp_sum_step<0x118>(x); y = dpp_sum_step<0x118>(y); z = dpp_sum_step<0x118>(z);
  x = dpp_sum_step<0x142>(x); y = dpp_sum_step<0x142>(y); z = dpp_sum_step<0x142>(z);
  x = dpp_sum_step<0x143>(x); y = dpp_sum_step<0x143>(y); z = dpp_sum_step<0x143>(z);
}
template <int CTRL>
__device__ __forceinline__ float dpp_mov_self(float x) {
  int s = __builtin_amdgcn_update_dpp(__float_as_int(x), __float_as_int(x), CTRL, 0xF, 0xF, false);
  return __int_as_float(s);
}
__device__ __forceinline__ float wave_min64(float x) {
  x = fminf(x, dpp_mov_self<0x111>(x));
  x = fminf(x, dpp_mov_self<0x112>(x));
  x = fminf(x, dpp_mov_self<0x114>(x));
  x = fminf(x, dpp_mov_self<0x118>(x));
  x = fminf(x, dpp_mov_self<0x142>(x));
  x = fminf(x, dpp_mov_self<0x143>(x));
  return x;  // min in lane 63
}
__device__ __forceinline__ float wave_max64(float x) {
  x = fmaxf(x, dpp_mov_self<0x111>(x));
  x = fmaxf(x, dpp_mov_self<0x112>(x));
  x = fmaxf(x, dpp_mov_self<0x114>(x));
  x = fmaxf(x, dpp_mov_self<0x118>(x));
  x = fmaxf(x, dpp_mov_self<0x142>(x));
  x = fmaxf(x, dpp_mov_self<0x143>(x));
  return x;  // max in lane 63
}
__device__ __forceinline__ float bcast63(float x) {
  return __int_as_float(__builtin_amdgcn_readlane(__float_as_int(x), 63));
}
__device__ __forceinline__ float clip1(float x) {
  return __builtin_amdgcn_fmed3f(x, -1.0f, 1.0f);  // c = MAX_WEIGHT = 1
}

// One block per batch element, 512 threads (8 waves). Thread (r = tid&127,
// q = tid>>7) owns QUARTER-row r, columns 32q..32q+31 -> 8 float4 = 32 VGPRs.
//
// R2-R7 forensic: allocator spills A-tiles past ~8 waves/EU budget; this
// layout keeps A register-resident at 4 blocks/CU, 32 waves/CU.
//
// R8 (this round): rocprof showed VALUBusy=50% @ occupancy 88% -> latency-
// bound on the serial bisection chain (~100cy/round x 40 on ONE wave while
// 7 waves barrier-wait, and blocks run in lockstep so nothing fills the
// lull). Fix: speculative 2-level bisection — evaluate s(m1), s(m2a), s(m2b)
// for both possible round-2 midpoints at once; the 3 DPP reduction chains
// are independent and pipeline. Resolves 2 bits per ~130cy instead of
// ~200cy, with a BIT-IDENTICAL lo/hi/mid/tau sequence (accuracy tripwire:
// absmax must stay exactly 2.288818e-3).
__global__ __launch_bounds__(NTHR)
void markowitz_kernel(
    const float* __restrict__ rets,
    const float* __restrict__ covmat,
    const float* __restrict__ gamma,
    const float* __restrict__ alpha,
    float* __restrict__ out)
{
  const int b    = blockIdx.x;
  const int tid  = threadIdx.x;
  const int r    = tid & (NA - 1);  // row 0..127
  const int q    = tid >> 7;        // quarter 0..3 (uniform within a wave)
  const int lane = tid & 63;
  const int wv   = tid >> 6;        // wave 0..7
  const int chain_wv = b & 7;       // which wave runs the bisection chain

  __shared__ __align__(16) float ws[NA];     // current weights
  __shared__ __align__(16) float vs[NA];     // pre-projection vector
  __shared__ __align__(16) float part[NTHR]; // quarter-row dot partials (part[tid])
  __shared__ float pp[4];                    // wAw, ww per wave 0/1

  // ---- one-time: stage quarter-row of A into registers, gamma folded ----
  const float gm = gamma[b];
  const float4* Aq = reinterpret_cast<const float4*>(
      covmat + (size_t)b * NA * NA + (size_t)r * NA + (size_t)q * 32);
  float4 a[8];
#pragma unroll
  for (int k = 0; k < 8; ++k) {
    float4 t = Aq[k];
    a[k] = make_float4(t.x * gm, t.y * gm, t.z * gm, t.w * gm);
  }
  const float av = fabsf(alpha[b]);
  float r_c = 0.0f;
  if (tid < NA) { r_c = rets[b * NA + tid]; ws[tid] = 1.0f / NA; }
  __syncthreads();

#pragma unroll 1
  for (int it = 0; it < NIT; ++it) {
    // ---- 1. quarter-row dot (A in regs; w via wave-uniform LDS broadcast) ----
    const float4* w4 = reinterpret_cast<const float4*>(ws) + q * 8;
    float4 acc = make_float4(0.f, 0.f, 0.f, 0.f);
#pragma unroll
    for (int k = 0; k < 8; ++k) {
      float4 wk = w4[k];  // uniform address within wave -> broadcast b128
      acc.x = fmaf(a[k].x, wk.x, acc.x);
      acc.y = fmaf(a[k].y, wk.y, acc.y);
      acc.z = fmaf(a[k].z, wk.z, acc.z);
      acc.w = fmaf(a[k].w, wk.w, acc.w);
    }
    part[tid] = (acc.x + acc.y) + (acc.z + acc.w);
    __syncthreads();

    // ---- 2. combine quarters; wAw / ww reductions (waves 0,1) ----
    float Aw = 0.f, w_c = 0.f, v_c = 0.f;
    if (tid < NA) {
      Aw  = (part[tid] + part[tid + NA]) + (part[tid + 2 * NA] + part[tid + 3 * NA]);
      w_c = ws[tid];
      float p1 = wave_sum64(w_c * Aw);
      float p2 = wave_sum64(w_c * w_c);
      if (lane == 63) { pp[wv * 2 + 0] = p1; pp[wv * 2 + 1] = p2; }
    }
    __syncthreads();

    // ---- 3. gradient step -> v (waves 0,1) ----
    if (tid < NA) {
      const float risk = sqrtf(pp[0] + pp[2] + EPSC);
      const float nrm  = sqrtf(pp[1] + pp[3] + EPSC);
      const float g    = r_c - Aw / risk - av * (w_c / nrm);
      v_c = w_c + LRC * g;
      vs[tid] = v_c;
    }
    __syncthreads();

    // ---- 4. bisection + projection on the chain wave only ----
    // Speculative 2-level bisection: the two possible next midpoints after
    // m1 are m2a = 0.5(lo+m1) (if s(m1)<=1) and m2b = 0.5(m1+hi) (if
    // s(m1)>1) — exactly the fp values the serial loop would compute. All
    // three sums are evaluated concurrently (pipelined DPP chains), then 2
    // bits are resolved branchlessly. Sequence is bit-identical to NBIS=40.
    if (wv == chain_wv) {
      float v0 = vs[lane];
      float v1 = vs[lane + 64];
      float mn = bcast63(wave_min64(fminf(v0, v1)));
      float mx = bcast63(wave_max64(fmaxf(v0, v1)));
      float lo = mn - 2.0f;   // min(v) - c - 1
      float hi = mx + 1.0f;   // max(v) + c
#pragma unroll 1
      for (int rr = 0; rr < NSUP; ++rr) {
        const float m1  = 0.5f * (lo + hi);
        const float m2a = 0.5f * (lo + m1);   // == serial mid if !b1
        const float m2b = 0.5f * (m1 + hi);   // == serial mid if  b1
        float s1  = clip1(v0 - m1)  + clip1(v1 - m1);
        float s2a = clip1(v0 - m2a) + clip1(v1 - m2a);
        float s2b = clip1(v0 - m2b) + clip1(v1 - m2b);
        wave_sum64_x3(s1, s2a, s2b);
        const bool  b1  = bcast63(s1) > 1.0f;
        const float st2 = b1 ? bcast63(s2b) : bcast63(s2a);
        const bool  b2  = st2 > 1.0f;
        // round 1: b1 ? (lo=m1)        : (hi=m1)
        // round 2: b1 ? (b2? lo=m2b : hi=m2b) : (b2? lo=m2a : hi=m2a)
        lo = b1 ? (b2 ? m2b : m1) : (b2 ? m2a : lo);
        hi = b1 ? (b2 ? hi : m2b) : (b2 ? m1  : m2a);
      }
      const float tau = 0.5f * (lo + hi);
      ws[lane]      = clip1(v0 - tau);
      ws[lane + 64] = clip1(v1 - tau);
    }
    __syncthreads();
  }

  if (tid < NA) out[b * NA + tid] = ws[tid];
}

extern "C" void kernel_launch(void* const* d_in, const int* in_sizes, int n_in,
                              void* d_out, int out_size, void* d_ws, size_t ws_size,
                              hipStream_t stream) {
  const float* rets   = (const float*)d_in[0];
  const float* covmat = (const float*)d_in[1];
  const float* gamma  = (const float*)d_in[2];
  const float* alpha  = (const float*)d_in[3];
  float* out = (float*)d_out;

  hipLaunchKernelGGL(markowitz_kernel, dim3(NBATCH), dim3(NTHR), 0, stream,
                     rets, covmat, gamma, alpha, out);
}

// Round 2
// 3004.733 us; speedup vs baseline: 1.0218x; 1.0218x over previous
//
#include <hip/hip_runtime.h>
#include <math.h>

#define NA      128
#define NBATCH  2048
#define NTHR    512
#define NIT     300
#define NBIS    40      // full 40: R7 showed NBIS=24 -> absmax 8e-3 (4e4x amplification of tau noise)
#define LRC     0.02f
#define EPSC    1e-8f

// ---- wave64 cross-lane reductions via DPP (VALU pipe, no LDS traffic) ----
// R8 lesson: DPP cross-lane ops from ONE wave issue at a fixed slow rate
// (~15cy/op) that independent same-wave work cannot fill (3-way speculative
// interleave scaled time by instruction count, not latency). Serial chain is
// the per-wave optimum; the lull must be filled by OTHER waves (see desync).
template <int CTRL>
__device__ __forceinline__ float dpp_sum_step(float x) {
  int s = __builtin_amdgcn_update_dpp(0, __float_as_int(x), CTRL, 0xF, 0xF, true);
  return x + __int_as_float(s);
}
__device__ __forceinline__ float wave_sum64(float x) {
  x = dpp_sum_step<0x111>(x);
  x = dpp_sum_step<0x112>(x);
  x = dpp_sum_step<0x114>(x);
  x = dpp_sum_step<0x118>(x);
  x = dpp_sum_step<0x142>(x);
  x = dpp_sum_step<0x143>(x);
  return x;  // total in lane 63
}
template <int CTRL>
__device__ __forceinline__ float dpp_mov_self(float x) {
  int s = __builtin_amdgcn_update_dpp(__float_as_int(x), __float_as_int(x), CTRL, 0xF, 0xF, false);
  return __int_as_float(s);
}
__device__ __forceinline__ float wave_min64(float x) {
  x = fminf(x, dpp_mov_self<0x111>(x));
  x = fminf(x, dpp_mov_self<0x112>(x));
  x = fminf(x, dpp_mov_self<0x114>(x));
  x = fminf(x, dpp_mov_self<0x118>(x));
  x = fminf(x, dpp_mov_self<0x142>(x));
  x = fminf(x, dpp_mov_self<0x143>(x));
  return x;  // min in lane 63
}
__device__ __forceinline__ float wave_max64(float x) {
  x = fmaxf(x, dpp_mov_self<0x111>(x));
  x = fmaxf(x, dpp_mov_self<0x112>(x));
  x = fmaxf(x, dpp_mov_self<0x114>(x));
  x = fmaxf(x, dpp_mov_self<0x118>(x));
  x = fmaxf(x, dpp_mov_self<0x142>(x));
  x = fmaxf(x, dpp_mov_self<0x143>(x));
  return x;  // max in lane 63
}
__device__ __forceinline__ float bcast63(float x) {
  return __int_as_float(__builtin_amdgcn_readlane(__float_as_int(x), 63));
}
__device__ __forceinline__ float clip1(float x) {
  return __builtin_amdgcn_fmed3f(x, -1.0f, 1.0f);  // c = MAX_WEIGHT = 1
}

// One block per batch element, 512 threads (8 waves). Thread (r = tid&127,
// q = tid>>7) owns QUARTER-row r, columns 32q..32q+31 -> 8 float4 = 32 VGPRs.
//
// R9 (this round), two orthogonal fixes, arithmetic bit-identical:
//  (1) A-PIN: VGPR_Count=32 + FETCH 66.5GB proved the allocator STILL remats
//      the whole A-tile every iteration (R2-R7 problem). The "+v" asm
//      keep-alive makes a[] an opaque loop-carried definition -> remat
//      illegal -> A truly register-resident. launch_bounds(512,8) caps the
//      allocator at 64 VGPRs (8 waves/EU, 4 blocks/CU) so demand ~56 fits.
//  (2) DESYNC: all co-resident blocks bisect in lockstep -> SIMDs ~80% idle
//      for ~half of each iteration (VALUBusy 50%). One-time per-block spin
//      (slot x ~1.15us) staggers phases so neighbors' matvec issue fills the
//      bisect lull. Durations are data-independent -> stagger self-preserves.
__global__ __launch_bounds__(NTHR, 8)
void markowitz_kernel(
    const float* __restrict__ rets,
    const float* __restrict__ covmat,
    const float* __restrict__ gamma,
    const float* __restrict__ alpha,
    float* __restrict__ out)
{
  const int b    = blockIdx.x;
  const int tid  = threadIdx.x;
  const int r    = tid & (NA - 1);  // row 0..127
  const int q    = tid >> 7;        // quarter 0..3 (uniform within a wave)
  const int lane = tid & 63;
  const int wv   = tid >> 6;        // wave 0..7
  // chain wave: mixed so co-resident blocks land chains on different SIMDs
  // under both plausible block->CU mappings (consecutive, or stride-256 via
  // XCD round-robin).
  const int chain_wv = ((b >> 8) + b) & 7;

  __shared__ __align__(16) float ws[NA];     // current weights
  __shared__ __align__(16) float vs[NA];     // pre-projection vector
  __shared__ __align__(16) float part[NTHR]; // quarter-row dot partials (part[tid])
  __shared__ float pp[4];                    // wAw, ww per wave 0/1

  // ---- one-time: stage quarter-row of A into registers, gamma folded ----
  const float gm = gamma[b];
  const float4* Aq = reinterpret_cast<const float4*>(
      covmat + (size_t)b * NA * NA + (size_t)r * NA + (size_t)q * 32);
  float4 a[8];
#pragma unroll
  for (int k = 0; k < 8; ++k) {
    float4 t = Aq[k];
    a[k] = make_float4(t.x * gm, t.y * gm, t.z * gm, t.w * gm);
  }
  const float av = fabsf(alpha[b]);
  float r_c = 0.0f;
  if (tid < NA) { r_c = rets[b * NA + tid]; ws[tid] = 1.0f / NA; }

  // ---- one-time desync spin: stagger co-resident blocks by ~1.15us/slot ----
  // slot = ((b>>8)^b)&3 gives distinct slots for co-resident sets under both
  // consecutive {4c..4c+3} and strided {c, c+256, ...} mappings.
  {
    const uint32_t slot = (uint32_t)(((b >> 8) ^ b) & 3);
    if (slot) {
      const uint64_t t0  = __builtin_amdgcn_s_memrealtime();  // 100 MHz ref
      const uint64_t dly = (uint64_t)slot * 115;              // ~1.15us/slot
      while (__builtin_amdgcn_s_memrealtime() - t0 < dly) { }
    }
  }
  __syncthreads();

#pragma unroll 1
  for (int it = 0; it < NIT; ++it) {
    // ---- A-pin: opaque loop-carried redefinition, remat illegal ----
#pragma unroll
    for (int k = 0; k < 8; ++k) {
      asm volatile("" : "+v"(a[k].x), "+v"(a[k].y), "+v"(a[k].z), "+v"(a[k].w));
    }

    // ---- 1. quarter-row dot (A in regs; w via wave-uniform LDS broadcast) ----
    const float4* w4 = reinterpret_cast<const float4*>(ws) + q * 8;
    float4 acc = make_float4(0.f, 0.f, 0.f, 0.f);
#pragma unroll
    for (int k = 0; k < 8; ++k) {
      float4 wk = w4[k];  // uniform address within wave -> broadcast b128
      acc.x = fmaf(a[k].x, wk.x, acc.x);
      acc.y = fmaf(a[k].y, wk.y, acc.y);
      acc.z = fmaf(a[k].z, wk.z, acc.z);
      acc.w = fmaf(a[k].w, wk.w, acc.w);
    }
    part[tid] = (acc.x + acc.y) + (acc.z + acc.w);
    __syncthreads();

    // ---- 2. combine quarters; wAw / ww reductions (waves 0,1) ----
    float Aw = 0.f, w_c = 0.f, v_c = 0.f;
    if (tid < NA) {
      Aw  = (part[tid] + part[tid + NA]) + (part[tid + 2 * NA] + part[tid + 3 * NA]);
      w_c = ws[tid];
      float p1 = wave_sum64(w_c * Aw);
      float p2 = wave_sum64(w_c * w_c);
      if (lane == 63) { pp[wv * 2 + 0] = p1; pp[wv * 2 + 1] = p2; }
    }
    __syncthreads();

    // ---- 3. gradient step -> v (waves 0,1) ----
    if (tid < NA) {
      const float risk = sqrtf(pp[0] + pp[2] + EPSC);
      const float nrm  = sqrtf(pp[1] + pp[3] + EPSC);
      const float g    = r_c - Aw / risk - av * (w_c / nrm);
      v_c = w_c + LRC * g;
      vs[tid] = v_c;
    }
    __syncthreads();

    // ---- 4. bisection + projection on the chain wave only (serial, NBIS=40) ----
    if (wv == chain_wv) {
      float v0 = vs[lane];
      float v1 = vs[lane + 64];
      float mn = bcast63(wave_min64(fminf(v0, v1)));
      float mx = bcast63(wave_max64(fmaxf(v0, v1)));
      float lo = mn - 2.0f;   // min(v) - c - 1
      float hi = mx + 1.0f;   // max(v) + c
#pragma unroll 1
      for (int rr = 0; rr < NBIS; ++rr) {
        const float mid = 0.5f * (lo + hi);
        float s = wave_sum64(clip1(v0 - mid) + clip1(v1 - mid));
        const float st = bcast63(s);
        const bool big = st > 1.0f;
        lo = big ? mid : lo;
        hi = big ? hi : mid;
      }
      const float tau = 0.5f * (lo + hi);
      ws[lane]      = clip1(v0 - tau);
      ws[lane + 64] = clip1(v1 - tau);
    }
    __syncthreads();
  }

  if (tid < NA) out[b * NA + tid] = ws[tid];
}

extern "C" void kernel_launch(void* const* d_in, const int* in_sizes, int n_in,
                              void* d_out, int out_size, void* d_ws, size_t ws_size,
                              hipStream_t stream) {
  const float* rets   = (const float*)d_in[0];
  const float* covmat = (const float*)d_in[1];
  const float* gamma  = (const float*)d_in[2];
  const float* alpha  = (const float*)d_in[3];
  float* out = (float*)d_out;

  hipLaunchKernelGGL(markowitz_kernel, dim3(NBATCH), dim3(NTHR), 0, stream,
                     rets, covmat, gamma, alpha, out);
}

// Round 3
// 2722.450 us; speedup vs baseline: 1.1278x; 1.1037x over previous
//
#include <hip/hip_runtime.h>
#include <math.h>

#define NA      128
#define NBATCH  2048
#define NTHR    512
#define NIT     300
#define NBIS    40      // full 40: R7 showed NBIS=24 -> absmax 8e-3 (4e4x amplification of tau noise)
#define LRC     0.02f
#define EPSC    1e-8f

// ---- wave64 cross-lane reductions via DPP (VALU pipe, no LDS traffic) ----
// R8 lesson (reinterpreted in R10): the "slow DPP issue" was 4 co-resident
// blocks' chains serialized on ONE SIMD (chain_wv = b&7 is identical for
// co-resident blocks {c, c+256, c+512, c+768}). Per-wave serial chain is
// fine; the fix is SIMD placement, not fewer DPP ops.
template <int CTRL>
__device__ __forceinline__ float dpp_sum_step(float x) {
  int s = __builtin_amdgcn_update_dpp(0, __float_as_int(x), CTRL, 0xF, 0xF, true);
  return x + __int_as_float(s);
}
__device__ __forceinline__ float wave_sum64(float x) {
  x = dpp_sum_step<0x111>(x);
  x = dpp_sum_step<0x112>(x);
  x = dpp_sum_step<0x114>(x);
  x = dpp_sum_step<0x118>(x);
  x = dpp_sum_step<0x142>(x);
  x = dpp_sum_step<0x143>(x);
  return x;  // total in lane 63
}
template <int CTRL>
__device__ __forceinline__ float dpp_mov_self(float x) {
  int s = __builtin_amdgcn_update_dpp(__float_as_int(x), __float_as_int(x), CTRL, 0xF, 0xF, false);
  return __int_as_float(s);
}
__device__ __forceinline__ float wave_min64(float x) {
  x = fminf(x, dpp_mov_self<0x111>(x));
  x = fminf(x, dpp_mov_self<0x112>(x));
  x = fminf(x, dpp_mov_self<0x114>(x));
  x = fminf(x, dpp_mov_self<0x118>(x));
  x = fminf(x, dpp_mov_self<0x142>(x));
  x = fminf(x, dpp_mov_self<0x143>(x));
  return x;  // min in lane 63
}
__device__ __forceinline__ float wave_max64(float x) {
  x = fmaxf(x, dpp_mov_self<0x111>(x));
  x = fmaxf(x, dpp_mov_self<0x112>(x));
  x = fmaxf(x, dpp_mov_self<0x114>(x));
  x = fmaxf(x, dpp_mov_self<0x118>(x));
  x = fmaxf(x, dpp_mov_self<0x142>(x));
  x = fmaxf(x, dpp_mov_self<0x143>(x));
  return x;  // max in lane 63
}
__device__ __forceinline__ float bcast63(float x) {
  return __int_as_float(__builtin_amdgcn_readlane(__float_as_int(x), 63));
}
__device__ __forceinline__ float clip1(float x) {
  return __builtin_amdgcn_fmed3f(x, -1.0f, 1.0f);  // c = MAX_WEIGHT = 1
}

// One block per batch element, 512 threads (8 waves). Thread (r = tid&127,
// q = tid>>7) owns QUARTER-row r, columns 32q..32q+31 -> 8 float4 = 32 VGPRs.
// A streams through L1/L2 every iteration (allocator insists on 32 VGPRs;
// R9 proved forcing residency -> scratch spill, +34GB writes. FETCH units
// are KB: actual baseline HBM traffic ~66MB/dispatch -> streaming is cheap).
//
// R10 (this round): SIMD-placement fix, arithmetic bit-identical to the
// 2685us baseline. Baseline pinned ALL co-resident blocks' serial phases to
// the same SIMDs: chain_wv=b&7 is constant across {c,c+256,c+512,c+768}
// (4 bisect chains serialized on one SIMD, ~6400cy/iter), and reduce/update
// always ran on waves 0-1 (SIMDs 0,1). Now both are spread by
// mix=(b+(b>>8))&7: distinct mod 4 among co-resident blocks -> 1 chain per
// SIMD, reduce pairs split across SIMD pairs. Same ops, same lanes, same fp
// order -> absmax must stay exactly 2.288818e-3.
__global__ __launch_bounds__(NTHR)
void markowitz_kernel(
    const float* __restrict__ rets,
    const float* __restrict__ covmat,
    const float* __restrict__ gamma,
    const float* __restrict__ alpha,
    float* __restrict__ out)
{
  const int b    = blockIdx.x;
  const int tid  = threadIdx.x;
  const int r    = tid & (NA - 1);  // row 0..127
  const int q    = tid >> 7;        // quarter 0..3 (uniform within a wave)
  const int lane = tid & 63;
  const int wv   = tid >> 6;        // wave 0..7
  const int mix  = (b + (b >> 8)) & 7;  // distinct mod 4 across co-resident blocks
  const int chain_wv = mix;             // bisect chain wave -> SIMD mix&3
  const int rbase    = (mix & 3) << 1;  // reduce/update waves {rbase, rbase+1}
  const int at   = tid - (rbase << 6);  // element index within reduce window
  const bool ract = ((unsigned)at < NA);

  __shared__ __align__(16) float ws[NA];     // current weights
  __shared__ __align__(16) float vs[NA];     // pre-projection vector
  __shared__ __align__(16) float part[NTHR]; // quarter-row dot partials (part[tid])
  __shared__ float pp[4];                    // wAw, ww partials (relative wave 0/1)

  // ---- one-time: stage quarter-row of A into registers, gamma folded ----
  const float gm = gamma[b];
  const float4* Aq = reinterpret_cast<const float4*>(
      covmat + (size_t)b * NA * NA + (size_t)r * NA + (size_t)q * 32);
  float4 a[8];
#pragma unroll
  for (int k = 0; k < 8; ++k) {
    float4 t = Aq[k];
    a[k] = make_float4(t.x * gm, t.y * gm, t.z * gm, t.w * gm);
  }
  const float av = fabsf(alpha[b]);
  float r_c = 0.0f;
  if (ract) r_c = rets[b * NA + at];
  if (tid < NA) ws[tid] = 1.0f / NA;
  __syncthreads();

#pragma unroll 1
  for (int it = 0; it < NIT; ++it) {
    // ---- 1. quarter-row dot (A streamed; w via wave-uniform LDS broadcast) ----
    const float4* w4 = reinterpret_cast<const float4*>(ws) + q * 8;
    float4 acc = make_float4(0.f, 0.f, 0.f, 0.f);
#pragma unroll
    for (int k = 0; k < 8; ++k) {
      float4 wk = w4[k];  // uniform address within wave -> broadcast b128
      acc.x = fmaf(a[k].x, wk.x, acc.x);
      acc.y = fmaf(a[k].y, wk.y, acc.y);
      acc.z = fmaf(a[k].z, wk.z, acc.z);
      acc.w = fmaf(a[k].w, wk.w, acc.w);
    }
    part[tid] = (acc.x + acc.y) + (acc.z + acc.w);
    __syncthreads();

    // ---- 2. combine quarters; wAw / ww reductions (block-dependent wave pair) ----
    // Element e lives at lane e&63 in both the old (waves 0-1) and new
    // (waves rbase..rbase+1) layouts -> identical reduction trees.
    float Aw = 0.f, w_c = 0.f;
    if (ract) {
      Aw  = (part[at] + part[at + NA]) + (part[at + 2 * NA] + part[at + 3 * NA]);
      w_c = ws[at];
      float p1 = wave_sum64(w_c * Aw);
      float p2 = wave_sum64(w_c * w_c);
      if (lane == 63) { int wr = at >> 6; pp[wr * 2 + 0] = p1; pp[wr * 2 + 1] = p2; }
    }
    __syncthreads();

    // ---- 3. gradient step -> v (same wave pair) ----
    if (ract) {
      const float risk = sqrtf(pp[0] + pp[2] + EPSC);
      const float nrm  = sqrtf(pp[1] + pp[3] + EPSC);
      const float g    = r_c - Aw / risk - av * (w_c / nrm);
      vs[at] = w_c + LRC * g;
    }
    __syncthreads();

    // ---- 4. bisection + projection on the chain wave only (serial, NBIS=40) ----
    if (wv == chain_wv) {
      float v0 = vs[lane];
      float v1 = vs[lane + 64];
      float mn = bcast63(wave_min64(fminf(v0, v1)));
      float mx = bcast63(wave_max64(fmaxf(v0, v1)));
      float lo = mn - 2.0f;   // min(v) - c - 1
      float hi = mx + 1.0f;   // max(v) + c
#pragma unroll 1
      for (int rr = 0; rr < NBIS; ++rr) {
        const float mid = 0.5f * (lo + hi);
        float s = wave_sum64(clip1(v0 - mid) + clip1(v1 - mid));
        const float st = bcast63(s);
        const bool big = st > 1.0f;
        lo = big ? mid : lo;
        hi = big ? hi : mid;
      }
      const float tau = 0.5f * (lo + hi);
      ws[lane]      = clip1(v0 - tau);
      ws[lane + 64] = clip1(v1 - tau);
    }
    __syncthreads();
  }

  if (tid < NA) out[b * NA + tid] = ws[tid];
}

extern "C" void kernel_launch(void* const* d_in, const int* in_sizes, int n_in,
                              void* d_out, int out_size, void* d_ws, size_t ws_size,
                              hipStream_t stream) {
  const float* rets   = (const float*)d_in[0];
  const float* covmat = (const float*)d_in[1];
  const float* gamma  = (const float*)d_in[2];
  const float* alpha  = (const float*)d_in[3];
  float* out = (float*)d_out;

  hipLaunchKernelGGL(markowitz_kernel, dim3(NBATCH), dim3(NTHR), 0, stream,
                     rets, covmat, gamma, alpha, out);
}